// Round 4
// baseline (97.623 us; speedup 1.0000x reference)
//
#include <hip/hip_runtime.h>

// Per-channel symmetric quantization, channel_axis=0.
// weights: [4096, 16384] f32.  Outputs flat in d_out (all f32):
//   q [4096*16384], scale [4096], zero_point [4096] (zeros).
//
// Persistent blocks: 2048 blocks x 512 threads, each block handles 2
// consecutive rows. Row staged in registers (8 x float4 = 32 VGPR),
// absmax via wave shfl_xor + LDS cross-wave, quantize from registers.
// Row r+1's loads issue right after row r's stores (no vmcnt wait on
// stores) -> the store-phase read bubble is filled intra-block.
// Nontemporal on both touch-once streams. <=64 VGPR tier (32 waves/CU).

#define ROWS 4096
#define COLS 16384
#define THREADS 512
#define ROWS_PER_BLOCK 2
#define BLOCKS (ROWS / ROWS_PER_BLOCK)
#define F4_PER_ROW (COLS / 4)            // 4096 float4 per row
#define ITERS (F4_PER_ROW / THREADS)     // 8 float4 per thread
#define NWAVES (THREADS / 64)            // 8 waves

typedef float f32x4 __attribute__((ext_vector_type(4)));

__global__ __launch_bounds__(THREADS, 8)
void quant_perchannel_kernel(const float* __restrict__ w,
                             const int* __restrict__ bits_ptr,
                             float* __restrict__ q_out,
                             float* __restrict__ scale_out,
                             float* __restrict__ zp_out) {
    const int tid = threadIdx.x;
    const int wave = tid >> 6;
    const int bits = bits_ptr[0];
    const float qmax = (float)((1 << (bits - 1)) - 1);   // 127 for 8 bits

    __shared__ float smax[NWAVES];

#pragma unroll
    for (int rr = 0; rr < ROWS_PER_BLOCK; ++rr) {
        const int row = blockIdx.x * ROWS_PER_BLOCK + rr;

        const f32x4* wrow =
            reinterpret_cast<const f32x4*>(w) + (size_t)row * F4_PER_ROW;

        // Stage row in registers (nontemporal), track per-thread absmax.
        f32x4 v[ITERS];
        float m = 0.0f;
#pragma unroll
        for (int i = 0; i < ITERS; ++i) {
            v[i] = __builtin_nontemporal_load(&wrow[i * THREADS + tid]);
            m = fmaxf(m, fmaxf(fmaxf(fabsf(v[i].x), fabsf(v[i].y)),
                               fmaxf(fabsf(v[i].z), fabsf(v[i].w))));
        }

        // Wave (64-lane) butterfly max reduction.
#pragma unroll
        for (int off = 1; off < 64; off <<= 1)
            m = fmaxf(m, __shfl_xor(m, off, 64));

        // Cross-wave via LDS.
        if (rr > 0) __syncthreads();     // protect smax reuse across rows
        if ((tid & 63) == 0) smax[wave] = m;
        __syncthreads();
        float bm = smax[0];
#pragma unroll
        for (int i = 1; i < NWAVES; ++i) bm = fmaxf(bm, smax[i]);

        const float scale = (bm > 0.0f) ? (bm / qmax) : 1.0f;
        const float inv = 1.0f / scale;

        // Quantize from registers (round-half-to-even), nontemporal store.
        f32x4* qrow =
            reinterpret_cast<f32x4*>(q_out) + (size_t)row * F4_PER_ROW;
#pragma unroll
        for (int i = 0; i < ITERS; ++i) {
            f32x4 r;
            r.x = fminf(fmaxf(rintf(v[i].x * inv), -qmax), qmax);
            r.y = fminf(fmaxf(rintf(v[i].y * inv), -qmax), qmax);
            r.z = fminf(fmaxf(rintf(v[i].z * inv), -qmax), qmax);
            r.w = fminf(fmaxf(rintf(v[i].w * inv), -qmax), qmax);
            __builtin_nontemporal_store(r, &qrow[i * THREADS + tid]);
        }

        if (tid == 0) {
            scale_out[row] = scale;
            zp_out[row] = 0.0f;
        }
    }
}

extern "C" void kernel_launch(void* const* d_in, const int* in_sizes, int n_in,
                              void* d_out, int out_size, void* d_ws, size_t ws_size,
                              hipStream_t stream) {
    const float* w = (const float*)d_in[0];
    const int* bits = (const int*)d_in[1];

    float* out = (float*)d_out;
    float* q_out = out;                                  // 4096*16384
    float* scale_out = out + (size_t)ROWS * COLS;        // 4096
    float* zp_out = scale_out + ROWS;                    // 4096

    quant_perchannel_kernel<<<BLOCKS, THREADS, 0, stream>>>(w, bits, q_out,
                                                            scale_out, zp_out);
}

// Round 5
// 93.044 us; speedup vs baseline: 1.0492x; 1.0492x over previous
//
#include <hip/hip_runtime.h>

// Per-channel symmetric quantization, channel_axis=0.
// weights: [4096, 16384] f32.  Outputs flat in d_out (all f32):
//   q [4096*16384], scale [4096], zero_point [4096] (zeros).
//
// R3 structure (best measured: 93.2 us = 5.76 TB/s effective on 537 MB).
// One block per row, 512 threads, 8 x float4 per thread staged in registers
// (32 VGPRs) -> <=64 VGPR tier, 32 waves/CU. Weights read from HBM exactly
// once. Nontemporal on both touch-once streams. Cross-block phase stagger
// (4 resident blocks/CU) hides the per-row reduce/store drain; R4 showed
// intra-block multi-row pipelining only regresses (97.6 us).

#define ROWS 4096
#define COLS 16384
#define THREADS 512
#define F4_PER_ROW (COLS / 4)            // 4096 float4 per row
#define ITERS (F4_PER_ROW / THREADS)     // 8 float4 per thread
#define NWAVES (THREADS / 64)            // 8 waves

typedef float f32x4 __attribute__((ext_vector_type(4)));

__global__ __launch_bounds__(THREADS, 8)
void quant_perchannel_kernel(const float* __restrict__ w,
                             const int* __restrict__ bits_ptr,
                             float* __restrict__ q_out,
                             float* __restrict__ scale_out,
                             float* __restrict__ zp_out) {
    const int row = blockIdx.x;
    const int tid = threadIdx.x;

    const f32x4* wrow = reinterpret_cast<const f32x4*>(w) + (size_t)row * F4_PER_ROW;

    // Stage row in registers (nontemporal: streaming, no reuse), track absmax.
    f32x4 v[ITERS];
    float m = 0.0f;
#pragma unroll
    for (int i = 0; i < ITERS; ++i) {
        v[i] = __builtin_nontemporal_load(&wrow[i * THREADS + tid]);
        m = fmaxf(m, fmaxf(fmaxf(fabsf(v[i].x), fabsf(v[i].y)),
                           fmaxf(fabsf(v[i].z), fabsf(v[i].w))));
    }

    // Wave (64-lane) butterfly max reduction.
#pragma unroll
    for (int off = 1; off < 64; off <<= 1)
        m = fmaxf(m, __shfl_xor(m, off, 64));

    // Across waves via LDS.
    __shared__ float smax[NWAVES];
    const int wave = tid >> 6;
    if ((tid & 63) == 0) smax[wave] = m;
    __syncthreads();
    float bm = smax[0];
#pragma unroll
    for (int i = 1; i < NWAVES; ++i) bm = fmaxf(bm, smax[i]);

    const int bits = bits_ptr[0];
    const float qmax = (float)((1 << (bits - 1)) - 1);   // 127 for 8 bits
    const float scale = (bm > 0.0f) ? (bm / qmax) : 1.0f;
    const float inv = 1.0f / scale;

    // Quantize from registers, round-half-to-even, nontemporal store.
    f32x4* qrow = reinterpret_cast<f32x4*>(q_out) + (size_t)row * F4_PER_ROW;
#pragma unroll
    for (int i = 0; i < ITERS; ++i) {
        f32x4 r;
        r.x = fminf(fmaxf(rintf(v[i].x * inv), -qmax), qmax);
        r.y = fminf(fmaxf(rintf(v[i].y * inv), -qmax), qmax);
        r.z = fminf(fmaxf(rintf(v[i].z * inv), -qmax), qmax);
        r.w = fminf(fmaxf(rintf(v[i].w * inv), -qmax), qmax);
        __builtin_nontemporal_store(r, &qrow[i * THREADS + tid]);
    }

    if (tid == 0) {
        scale_out[row] = scale;
        zp_out[row] = 0.0f;
    }
}

extern "C" void kernel_launch(void* const* d_in, const int* in_sizes, int n_in,
                              void* d_out, int out_size, void* d_ws, size_t ws_size,
                              hipStream_t stream) {
    const float* w = (const float*)d_in[0];
    const int* bits = (const int*)d_in[1];

    float* out = (float*)d_out;
    float* q_out = out;                                  // 4096*16384
    float* scale_out = out + (size_t)ROWS * COLS;        // 4096
    float* zp_out = scale_out + ROWS;                    // 4096

    quant_perchannel_kernel<<<ROWS, THREADS, 0, stream>>>(w, bits, q_out,
                                                          scale_out, zp_out);
}